// Round 1
// 2620.977 us; speedup vs baseline: 1.0084x; 1.0084x over previous
//
#include <hip/hip_runtime.h>
#include <hip/hip_bf16.h>
#include <math.h>

#define DMODEL 4096
#define NROWS  8192          // B*N = 4*2048
#define DFF    5461
#define CHUNK  512
#define NCHUNK 16
#define LNEPS  1e-5f

// split-fp16 MFMA GEMM params
#define GBM 128
#define GBN 128
#define GBK 32
#define LOSCALE 2048.0f      // 2^11
#define LOINV   4.8828125e-4f // 2^-11

typedef _Float16 h8 __attribute__((ext_vector_type(8)));
typedef _Float16 h4 __attribute__((ext_vector_type(4)));
typedef float floatx4 __attribute__((ext_vector_type(4)));

__device__ inline unsigned short f2bf(float f) {
    unsigned int x = __builtin_bit_cast(unsigned int, f);
    unsigned int r = x + 0x7FFFu + ((x >> 16) & 1u);   // RNE
    return (unsigned short)(r >> 16);
}
__device__ inline float bf2f(unsigned short u) {
    return __builtin_bit_cast(float, ((unsigned int)u) << 16);
}

#define GLL(gp, lp) __builtin_amdgcn_global_load_lds( \
    (const __attribute__((address_space(1))) void*)(gp), \
    (__attribute__((address_space(3))) void*)(lp), 16, 0, 0)

// ---------------- prep: silu(x) fp32 -> fp16 hi/lo split ----------------
__global__ __launch_bounds__(256) void silu_split_k(const float* __restrict__ x,
                                                    _Float16* __restrict__ xh,
                                                    _Float16* __restrict__ xl) {
    size_t i = (size_t)blockIdx.x * 256 + threadIdx.x;   // float4 index
    float4 v = ((const float4*)x)[i];
    float s[4];
    s[0] = v.x / (1.f + expf(-v.x));
    s[1] = v.y / (1.f + expf(-v.y));
    s[2] = v.z / (1.f + expf(-v.z));
    s[3] = v.w / (1.f + expf(-v.w));
    h4 hi, lo;
#pragma unroll
    for (int j = 0; j < 4; ++j) {
        _Float16 h = (_Float16)s[j];
        hi[j] = h;
        lo[j] = (_Float16)((s[j] - (float)h) * LOSCALE);
    }
    ((h4*)xh)[i] = hi;
    ((h4*)xl)[i] = lo;
}

// ---------------- prep: W_gates fp32 -> fp16 hi/lo split ----------------
__global__ __launch_bounds__(256) void wsplit_k(const float* __restrict__ Wg,
                                                _Float16* __restrict__ wh,
                                                _Float16* __restrict__ wl) {
    size_t i = (size_t)blockIdx.x * 256 + threadIdx.x;
    float4 v = ((const float4*)Wg)[i];
    float s[4] = {v.x, v.y, v.z, v.w};
    h4 hi, lo;
#pragma unroll
    for (int j = 0; j < 4; ++j) {
        _Float16 h = (_Float16)s[j];
        hi[j] = h;
        lo[j] = (_Float16)((s[j] - (float)h) * LOSCALE);
    }
    ((h4*)wh)[i] = hi;
    ((h4*)wl)[i] = lo;
}

// ---------------- block-diagonal gate GEMM, split-fp16 MFMA (~fp32 precision) ----------------
// pre[g, row, kb*1024 + o] = sum_i silu(x)[row, kb*1024+i] * Wg[g,kb,o,i]
// grid: x = 1024/GBN (=8), y = CHUNK/GBM (=4), z = 16 (g*4+kb)
__global__ __launch_bounds__(256, 2) void gemm_split_k(
    const _Float16* __restrict__ xh, const _Float16* __restrict__ xl,
    const _Float16* __restrict__ wh, const _Float16* __restrict__ wl,
    float* __restrict__ pre, int row0)
{
    __shared__ __align__(16) _Float16 Ah[GBM * GBK];   // 8 KB each, 32 KB total
    __shared__ __align__(16) _Float16 Al[GBM * GBK];
    __shared__ __align__(16) _Float16 Bh[GBN * GBK];
    __shared__ __align__(16) _Float16 Bl[GBN * GBK];

    const int gz = blockIdx.z;
    const int kb = gz & 3, g = gz >> 2;
    const int tM = blockIdx.y, tN = blockIdx.x;
    const int t = threadIdx.x;
    const int w = t >> 6, l = t & 63;
    const int lane15 = l & 15, quad = l >> 4;
    const int wm = w >> 1, wn = w & 1;

    const size_t Aoff = (size_t)(row0 + tM * GBM) * DMODEL + kb * 1024;
    const size_t Boff = (size_t)gz * (1024 * 1024) + (size_t)(tN * GBN) * 1024;

    floatx4 acc_h[4][4] = {};
    floatx4 acc_x[4][4] = {};

    for (int kt = 0; kt < 1024; kt += GBK) {
        const _Float16* ahs = xh + Aoff + kt;
        const _Float16* als = xl + Aoff + kt;
        const _Float16* bhs = wh + Boff + kt;
        const _Float16* bls = wl + Boff + kt;
#pragma unroll
        for (int it = 0; it < 2; ++it) {
            const int chunk = it * 256 + t;       // 0..511 16B-chunks per tile
            const int r = chunk >> 2;             // tile row 0..127
            const int c = (chunk & 3) * 8;        // k-offset in halfs
            const int lo = (it * 256 + w * 64) * 8;  // wave-uniform LDS base (elements)
            const size_t ga = (size_t)r * DMODEL + c;
            const size_t gb = (size_t)r * 1024 + c;
            GLL(ahs + ga, Ah + lo);
            GLL(als + ga, Al + lo);
            GLL(bhs + gb, Bh + lo);
            GLL(bls + gb, Bl + lo);
        }
        __syncthreads();

        h8 af[4], alf[4], bf[4], blf[4];
#pragma unroll
        for (int mi = 0; mi < 4; ++mi) {
            const int ro = (wm * 64 + mi * 16 + lane15) * GBK + quad * 8;
            af[mi]  = *(const h8*)&Ah[ro];
            alf[mi] = *(const h8*)&Al[ro];
        }
#pragma unroll
        for (int ni = 0; ni < 4; ++ni) {
            const int ro = (wn * 64 + ni * 16 + lane15) * GBK + quad * 8;
            bf[ni]  = *(const h8*)&Bh[ro];
            blf[ni] = *(const h8*)&Bl[ro];
        }
#pragma unroll
        for (int mi = 0; mi < 4; ++mi)
#pragma unroll
            for (int ni = 0; ni < 4; ++ni) {
                acc_h[mi][ni] = __builtin_amdgcn_mfma_f32_16x16x32_f16(
                    af[mi], bf[ni], acc_h[mi][ni], 0, 0, 0);
                acc_x[mi][ni] = __builtin_amdgcn_mfma_f32_16x16x32_f16(
                    af[mi], blf[ni], acc_x[mi][ni], 0, 0, 0);
                acc_x[mi][ni] = __builtin_amdgcn_mfma_f32_16x16x32_f16(
                    alf[mi], bf[ni], acc_x[mi][ni], 0, 0, 0);
            }
        __syncthreads();
    }

#pragma unroll
    for (int mi = 0; mi < 4; ++mi) {
#pragma unroll
        for (int r = 0; r < 4; ++r) {
            const int rowl = tM * GBM + wm * 64 + mi * 16 + quad * 4 + r;
            float* dst = pre + ((size_t)g * CHUNK + rowl) * DMODEL
                         + kb * 1024 + tN * GBN + wn * 64 + lane15;
#pragma unroll
            for (int ni = 0; ni < 4; ++ni)
                dst[ni * 16] = acc_h[mi][ni][r] + acc_x[mi][ni][r] * LOINV;
        }
    }
}

// ---------------- block reduction helper (256 threads = 4 waves) ----------------
template <int N>
__device__ inline void block_reduce(float* s, float* red) {
    const int t = threadIdx.x, w = t >> 6, l = t & 63;
#pragma unroll
    for (int i = 0; i < N; ++i) {
        float v = s[i];
#pragma unroll
        for (int off = 32; off > 0; off >>= 1) v += __shfl_xor(v, off, 64);
        if (l == 0) red[w * N + i] = v;
    }
    __syncthreads();
#pragma unroll
    for (int i = 0; i < N; ++i)
        s[i] = red[0 * N + i] + red[1 * N + i] + red[2 * N + i] + red[3 * N + i];
    __syncthreads();
}

// ---------------- block reduction helper (1024 threads = 16 waves) ----------------
// Two-stage: intra-wave butterfly -> red[i*16+w]; waves 0..N/ reduce 16 partials
// per stat in 16-lane groups; finals broadcast from red[256+i].
template <int N>
__device__ inline void block_reduce16(float* s, float* red) {
    const int t = threadIdx.x, w = t >> 6, l = t & 63;
#pragma unroll
    for (int i = 0; i < N; ++i) {
        float v = s[i];
#pragma unroll
        for (int off = 32; off > 0; off >>= 1) v += __shfl_xor(v, off, 64);
        if (l == 0) red[i * 16 + w] = v;
    }
    __syncthreads();
    if (t < 16 * N) {                 // stat i = t>>4, wave-slot = t&15 (full 16-lane groups)
        float v = red[t];
#pragma unroll
        for (int off = 8; off > 0; off >>= 1) v += __shfl_xor(v, off, 64);
        if ((t & 15) == 0) red[256 + (t >> 4)] = v;
    }
    __syncthreads();
#pragma unroll
    for (int i = 0; i < N; ++i) s[i] = red[256 + i];   // broadcast read
}

// ---------------- fused LN + gates + ct/nt row accumulation (per chunk) ----------------
// 1024 threads: each thread owns elements d = 4t..4t+3 (full row in registers after
// ONE vectorized load pass). 2 rows per block, processed together -> only 2 reduction
// phases per block (was 6 serial scalar passes at 4 waves/CU). 16 waves/CU.
__global__ __launch_bounds__(1024) void lnpass_k(
    const float* __restrict__ pre, const float* __restrict__ bg,
    const float* __restrict__ lng, const float* __restrict__ lnb,
    unsigned short* __restrict__ obuf,
    float* __restrict__ ctv, float* __restrict__ ntv, int row0)
{
    __shared__ float red[272];
    const int t = threadIdx.x;
    const int d0 = 4 * t;
    const float n1 = 1.f / DMODEL;
    const int rl0 = blockIdx.x * 2;

    // ---- pass 1: load both rows x 4 gates (float4 each), row stats ----
    float v[2][4][4];
    float s[16];
#pragma unroll
    for (int rr = 0; rr < 2; ++rr) {
#pragma unroll
        for (int g = 0; g < 4; ++g) {
            float4 pv = *(const float4*)(pre + ((size_t)g * CHUNK + rl0 + rr) * DMODEL + d0);
            float4 bv = *(const float4*)(bg + (size_t)g * DMODEL + d0);
            float a0 = pv.x + bv.x, a1 = pv.y + bv.y, a2 = pv.z + bv.z, a3 = pv.w + bv.w;
            v[rr][g][0] = a0; v[rr][g][1] = a1; v[rr][g][2] = a2; v[rr][g][3] = a3;
            s[rr * 8 + g * 2 + 0] = a0 + a1 + a2 + a3;
            s[rr * 8 + g * 2 + 1] = a0 * a0 + a1 * a1 + a2 * a2 + a3 * a3;
        }
    }
    block_reduce16<16>(s, red);

    float mu[2][4], rs[2][4];
#pragma unroll
    for (int rr = 0; rr < 2; ++rr)
#pragma unroll
        for (int g = 0; g < 4; ++g) {
            mu[rr][g] = s[rr * 8 + g * 2] * n1;
            rs[rr][g] = rsqrtf(s[rr * 8 + g * 2 + 1] * n1 - mu[rr][g] * mu[rr][g] + LNEPS);
        }

    // ---- gates from registers: i,f -> ct/nt locals; o -> obuf now ----
    float ctl[2][4], ntl[2][4];
    float s2[8];
#pragma unroll
    for (int rr = 0; rr < 2; ++rr) {
        float li[4], lf[4], zv[4], ov[4];
        {
            float4 gv = *(const float4*)(lng + d0);
            float4 bv = *(const float4*)(lnb + d0);
            float gg[4] = {gv.x, gv.y, gv.z, gv.w}, bb[4] = {bv.x, bv.y, bv.z, bv.w};
#pragma unroll
            for (int j = 0; j < 4; ++j)
                li[j] = (v[rr][0][j] - mu[rr][0]) * rs[rr][0] * gg[j] + bb[j];
        }
        {
            float4 gv = *(const float4*)(lng + DMODEL + d0);
            float4 bv = *(const float4*)(lnb + DMODEL + d0);
            float gg[4] = {gv.x, gv.y, gv.z, gv.w}, bb[4] = {bv.x, bv.y, bv.z, bv.w};
#pragma unroll
            for (int j = 0; j < 4; ++j)
                lf[j] = (v[rr][1][j] - mu[rr][1]) * rs[rr][1] * gg[j] + bb[j];
        }
        {
            float4 gv = *(const float4*)(lng + 2 * DMODEL + d0);
            float4 bv = *(const float4*)(lnb + 2 * DMODEL + d0);
            float gg[4] = {gv.x, gv.y, gv.z, gv.w}, bb[4] = {bv.x, bv.y, bv.z, bv.w};
#pragma unroll
            for (int j = 0; j < 4; ++j) {
                float o = (v[rr][2][j] - mu[rr][2]) * rs[rr][2] * gg[j] + bb[j];
                ov[j] = 1.f / (1.f + expf(-o));
            }
            ushort4 ou;
            ou.x = f2bf(ov[0]); ou.y = f2bf(ov[1]); ou.z = f2bf(ov[2]); ou.w = f2bf(ov[3]);
            *(ushort4*)(obuf + (size_t)(row0 + rl0 + rr) * DMODEL + d0) = ou;
        }
        {
            float4 gv = *(const float4*)(lng + 3 * DMODEL + d0);
            float4 bv = *(const float4*)(lnb + 3 * DMODEL + d0);
            float gg[4] = {gv.x, gv.y, gv.z, gv.w}, bb[4] = {bv.x, bv.y, bv.z, bv.w};
#pragma unroll
            for (int j = 0; j < 4; ++j)
                zv[j] = tanhf((v[rr][3][j] - mu[rr][3]) * rs[rr][3] * gg[j] + bb[j]);
        }
        float sc = 0.f, scc = 0.f, sn = 0.f, snn = 0.f;
#pragma unroll
        for (int j = 0; j < 4; ++j) {
            float iv = expf(fminf(li[j] - lf[j], 0.f));  // i = exp(log_i - max(log_i,log_f))
            float c = iv * zv[j];
            ctl[rr][j] = c; ntl[rr][j] = iv;
            sc += c;  scc += c * c;
            sn += iv; snn += iv * iv;
        }
        s2[rr * 4 + 0] = sc;  s2[rr * 4 + 1] = scc;
        s2[rr * 4 + 2] = sn;  s2[rr * 4 + 3] = snn;
    }
    block_reduce16<8>(s2, red);

    // ---- LN4/LN5 + accumulate into global ct/nt (2 rows amortized per atomic) ----
    float cmu[2], crs[2], nmu[2], nrs[2];
#pragma unroll
    for (int rr = 0; rr < 2; ++rr) {
        cmu[rr] = s2[rr * 4 + 0] * n1;
        crs[rr] = rsqrtf(s2[rr * 4 + 1] * n1 - cmu[rr] * cmu[rr] + LNEPS);
        nmu[rr] = s2[rr * 4 + 2] * n1;
        nrs[rr] = rsqrtf(s2[rr * 4 + 3] * n1 - nmu[rr] * nmu[rr] + LNEPS);
    }
    {
        float4 g4v = *(const float4*)(lng + 4 * DMODEL + d0);
        float4 b4v = *(const float4*)(lnb + 4 * DMODEL + d0);
        float4 g5v = *(const float4*)(lng + 5 * DMODEL + d0);
        float4 b5v = *(const float4*)(lnb + 5 * DMODEL + d0);
        float g4[4] = {g4v.x, g4v.y, g4v.z, g4v.w}, b4[4] = {b4v.x, b4v.y, b4v.z, b4v.w};
        float g5[4] = {g5v.x, g5v.y, g5v.z, g5v.w}, b5[4] = {b5v.x, b5v.y, b5v.z, b5v.w};
#pragma unroll
        for (int j = 0; j < 4; ++j) {
            float cta = (ctl[0][j] - cmu[0]) * crs[0] * g4[j] + b4[j]
                      + (ctl[1][j] - cmu[1]) * crs[1] * g4[j] + b4[j];
            float nta = (ntl[0][j] - nmu[0]) * nrs[0] * g5[j] + b5[j]
                      + (ntl[1][j] - nmu[1]) * nrs[1] * g5[j] + b5[j];
            atomicAdd(&ctv[d0 + j], cta);
            atomicAdd(&ntv[d0 + j], nta);
        }
    }
}

// ---------------- ht = o * (ctv/ntv), LN6 per row, accumulate row-mean ----------------
// 1024 threads, 4 rows batched per reduction phase (4 phases per block of 16 rows).
#define HROWS 16
__global__ __launch_bounds__(1024) void htpass_k(
    const unsigned short* __restrict__ obuf,
    const float* __restrict__ ctv, const float* __restrict__ ntv,
    const float* __restrict__ lng, const float* __restrict__ lnb,
    float* __restrict__ htv)
{
    __shared__ float red[272];
    const int t = threadIdx.x;
    const int d0 = 4 * t;
    const float n1 = 1.f / DMODEL;
    float r[4];
    {
        float4 c = *(const float4*)(ctv + d0);
        float4 n = *(const float4*)(ntv + d0);
        r[0] = c.x / n.x; r[1] = c.y / n.y; r[2] = c.z / n.z; r[3] = c.w / n.w;
    }
    float g6[4], b6[4];
    {
        float4 gv = *(const float4*)(lng + 6 * DMODEL + d0);
        float4 bv = *(const float4*)(lnb + 6 * DMODEL + d0);
        g6[0] = gv.x; g6[1] = gv.y; g6[2] = gv.z; g6[3] = gv.w;
        b6[0] = bv.x; b6[1] = bv.y; b6[2] = bv.z; b6[3] = bv.w;
    }
    float hacc[4] = {};
    for (int rt = 0; rt < HROWS; rt += 4) {
        float h[4][4];
        float s[8];
#pragma unroll
        for (int rr = 0; rr < 4; ++rr) {
            const int row = blockIdx.x * HROWS + rt + rr;
            ushort4 u = *(const ushort4*)(obuf + (size_t)row * DMODEL + d0);
            h[rr][0] = bf2f(u.x) * r[0];
            h[rr][1] = bf2f(u.y) * r[1];
            h[rr][2] = bf2f(u.z) * r[2];
            h[rr][3] = bf2f(u.w) * r[3];
            s[rr * 2 + 0] = h[rr][0] + h[rr][1] + h[rr][2] + h[rr][3];
            s[rr * 2 + 1] = h[rr][0] * h[rr][0] + h[rr][1] * h[rr][1]
                          + h[rr][2] * h[rr][2] + h[rr][3] * h[rr][3];
        }
        block_reduce16<8>(s, red);
#pragma unroll
        for (int rr = 0; rr < 4; ++rr) {
            const float mu = s[rr * 2] * n1;
            const float rsv = rsqrtf(s[rr * 2 + 1] * n1 - mu * mu + LNEPS);
#pragma unroll
            for (int j = 0; j < 4; ++j)
                hacc[j] += (h[rr][j] - mu) * rsv * g6[j] + b6[j];
        }
    }
#pragma unroll
    for (int j = 0; j < 4; ++j) atomicAdd(&htv[d0 + j], hacc[j]);
}

// ---------------- slstm_out = LN7(mean ht) ----------------
__global__ __launch_bounds__(256) void finalvec_k(
    const float* __restrict__ htv, const float* __restrict__ lng,
    const float* __restrict__ lnb, float* __restrict__ sout)
{
    __shared__ float red[8];
    const int t = threadIdx.x;
    const float n1 = 1.f / DMODEL;
    float v[16]; float s[2] = {};
    for (int j = 0; j < 16; ++j) {
        const int d = t + 256 * j;
        v[j] = htv[d] * (1.f / (float)NROWS);
        s[0] += v[j]; s[1] += v[j] * v[j];
    }
    block_reduce<2>(s, red);
    const float mu = s[0] * n1, rs = rsqrtf(s[1] * n1 - mu * mu + LNEPS);
    for (int j = 0; j < 16; ++j) {
        const int d = t + 256 * j;
        sout[d] = (v[j] - mu) * rs * lng[7 * DMODEL + d] + lnb[7 * DMODEL + d];
    }
}

// ---------------- left/right GEMV + exact gelu, one wave per output f ----------------
__global__ __launch_bounds__(256) void ffn1_k(
    const float* __restrict__ sout,
    const float* __restrict__ Wl, const float* __restrict__ bl,
    const float* __restrict__ Wr, const float* __restrict__ br,
    float* __restrict__ u)
{
    const int t = threadIdx.x, w = t >> 6, l = t & 63;
    const int f = blockIdx.x * 4 + w;
    if (f >= DFF) return;
    const float4* wl4 = (const float4*)(Wl + (size_t)f * DMODEL);
    const float4* wr4 = (const float4*)(Wr + (size_t)f * DMODEL);
    const float4* s4 = (const float4*)sout;
    float a = 0.f, b = 0.f;
#pragma unroll
    for (int jj = 0; jj < 16; ++jj) {
        const int i4 = l + 64 * jj;
        float4 sv = s4[i4], av = wl4[i4], bv = wr4[i4];
        a += sv.x * av.x + sv.y * av.y + sv.z * av.z + sv.w * av.w;
        b += sv.x * bv.x + sv.y * bv.y + sv.z * bv.z + sv.w * bv.w;
    }
#pragma unroll
    for (int off = 32; off > 0; off >>= 1) {
        a += __shfl_xor(a, off, 64);
        b += __shfl_xor(b, off, 64);
    }
    if (l == 0) {
        float lv = a + bl[f];
        float rv = b + br[f];
        float g = 0.5f * rv * (1.f + erff(rv * 0.70710678118654752f));  // exact gelu
        u[f] = lv * g;
    }
}

// ---------------- LN over DFF ----------------
__global__ __launch_bounds__(256) void lnout_k(
    const float* __restrict__ u, const float* __restrict__ g,
    const float* __restrict__ b, float* __restrict__ y)
{
    __shared__ float red[8];
    const int t = threadIdx.x;
    float s[2] = {};
    for (int d = t; d < DFF; d += 256) { float v = u[d]; s[0] += v; s[1] += v * v; }
    block_reduce<2>(s, red);
    const float n1 = 1.f / (float)DFF;
    const float mu = s[0] * n1, rs = rsqrtf(s[1] * n1 - mu * mu + LNEPS);
    for (int d = t; d < DFF; d += 256) y[d] = (u[d] - mu) * rs * g[d] + b[d];
}

// ---------------- proj GEMV, one wave per output d ----------------
__global__ __launch_bounds__(256) void ffn2_k(
    const float* __restrict__ y, const float* __restrict__ Wp,
    const float* __restrict__ bp, float* __restrict__ out)
{
    const int t = threadIdx.x, w = t >> 6, l = t & 63;
    const int d = blockIdx.x * 4 + w;
    const float* row = Wp + (size_t)d * DFF;
    float s = 0.f;
    for (int j = l; j < DFF; j += 64) s += row[j] * y[j];
#pragma unroll
    for (int off = 32; off > 0; off >>= 1) s += __shfl_xor(s, off, 64);
    if (l == 0) out[d] = s + bp[d];
}

extern "C" void kernel_launch(void* const* d_in, const int* in_sizes, int n_in,
                              void* d_out, int out_size, void* d_ws, size_t ws_size,
                              hipStream_t stream)
{
    const float* x   = (const float*)d_in[0];
    const float* Wg  = (const float*)d_in[1];
    const float* bg  = (const float*)d_in[2];
    // d_in[3] = Wr_gates: provably unused (ht_1 == 0)
    const float* lng = (const float*)d_in[4];
    const float* lnb = (const float*)d_in[5];
    const float* log_ = (const float*)d_in[6];
    const float* lob  = (const float*)d_in[7];
    const float* Wl  = (const float*)d_in[8];
    const float* bl  = (const float*)d_in[9];
    const float* Wr  = (const float*)d_in[10];
    const float* br  = (const float*)d_in[11];
    const float* Wp  = (const float*)d_in[12];
    const float* bp  = (const float*)d_in[13];
    float* out = (float*)d_out;

    char* ws = (char*)d_ws;
    size_t off = 0;
    _Float16* xh = (_Float16*)(ws + off); off += (size_t)NROWS * DMODEL * 2;        // 64 MB
    _Float16* xl = (_Float16*)(ws + off); off += (size_t)NROWS * DMODEL * 2;        // 64 MB
    _Float16* whp = (_Float16*)(ws + off); off += (size_t)16 * 1024 * 1024 * 2;     // 32 MB
    _Float16* wlp = (_Float16*)(ws + off); off += (size_t)16 * 1024 * 1024 * 2;     // 32 MB
    float* pre  = (float*)(ws + off); off += (size_t)4 * CHUNK * DMODEL * 4;        // 32 MB
    float* ctv  = (float*)(ws + off); off += DMODEL * 4;
    float* ntv  = (float*)(ws + off); off += DMODEL * 4;
    float* htv  = (float*)(ws + off); off += DMODEL * 4;
    float* sout = (float*)(ws + off); off += DMODEL * 4;
    float* u    = (float*)(ws + off); off += DFF * 4;
    float* y    = (float*)(ws + off); off += DFF * 4;

    // obuf aliases xl: chunk c's xl rows are last read by gemm(c), and obuf rows
    // [c*CHUNK, (c+1)*CHUNK) are written only by lnpass(c), which is stream-ordered
    // after gemm(c). htpass reads obuf after all chunks. Total ws stays at 224 MB.
    unsigned short* obuf = (unsigned short*)xl;

    // zero the global accumulators (ctv, ntv, htv are contiguous)
    hipMemsetAsync(ctv, 0, 3 * DMODEL * 4, stream);

    silu_split_k<<<(NROWS * DMODEL) / 1024, 256, 0, stream>>>(x, xh, xl);
    wsplit_k<<<(16 * 1024 * 1024) / 1024, 256, 0, stream>>>(Wg, whp, wlp);

    for (int c = 0; c < NCHUNK; ++c) {
        const int row0 = c * CHUNK;
        dim3 grid(1024 / GBN, CHUNK / GBM, 16);
        gemm_split_k<<<grid, 256, 0, stream>>>(xh, xl, whp, wlp, pre, row0);
        lnpass_k<<<CHUNK / 2, 1024, 0, stream>>>(pre, bg, lng, lnb, obuf, ctv, ntv, row0);
    }

    htpass_k<<<NROWS / HROWS, 1024, 0, stream>>>(obuf, ctv, ntv, lng, lnb, htv);
    finalvec_k<<<1, 256, 0, stream>>>(htv, lng, lnb, sout);
    ffn1_k<<<(DFF + 3) / 4, 256, 0, stream>>>(sout, Wl, bl, Wr, br, u);
    lnout_k<<<1, 256, 0, stream>>>(u, log_, lob, y);
    ffn2_k<<<DMODEL / 4, 256, 0, stream>>>(y, Wp, bp, out);

    (void)in_sizes; (void)n_in; (void)out_size; (void)ws_size;
}